// Round 1
// baseline (331.976 us; speedup 1.0000x reference)
//
#include <hip/hip_runtime.h>

// DeepNovo intensity-window gather.
// out[b][v][ion][w] = spectrum[round((ion_mass)*10) - 5 + w] * valid * label_mask[v]
// Output 32768*26*8*10 fp32 = 272.6 MB  -> HBM-write-bound (~43 us floor @6.3 TB/s).
// One thread per output float4: wave writes 64x16B contiguous (perfect coalescing).

#define MASS_H2O 18.01056f
#define MASS_NH3 17.02655f

constexpr int MAX_MZ = 30000;
constexpr int WIN = 10;
constexpr int VOCAB = 26;

__global__ __launch_bounds__(256) void intensity_kernel(
    const float* __restrict__ spectrum,
    const float* __restrict__ pepmass,
    const float* __restrict__ prefix_mass,
    const float* __restrict__ masses,
    const int*   __restrict__ dir_p,
    float* __restrict__ out,
    int n_vec4)
{
    int tid = blockIdx.x * blockDim.x + threadIdx.x;
    if (tid >= n_vec4) return;

    const int dir = dir_p[0];

    // Each (b,v) owns 80 contiguous floats = 20 float4s.
    int g = tid / 20;          // flat (b,v) group
    int q = tid - g * 20;      // which float4 inside the group [0,20)
    int b = g / VOCAB;
    int v = g - b * VOCAB;

    float pm = pepmass[b];
    float pf = prefix_mass[b];
    float ms = masses[v];

    float t = pf + ms;         // prefix + residue
    float u = pm - t;
    float cb = (dir == 0) ? t : u;
    float cy = (dir == 0) ? u : t;

    // vocab rows {PAD, GO, EOS} = {0,1,2} zeroed for both directions
    float lmask = (v > 2) ? 1.0f : 0.0f;

    float vals[4];
#pragma unroll
    for (int j = 0; j < 4; ++j) {
        int e   = 4 * q + j;       // element within the 80-float group
        int ion = e / WIN;         // 0..7
        int w   = e - ion * WIN;   // 0..9

        float m = (ion < 4) ? cb : cy;
        int k = ion & 3;
        m = (k == 1) ? (m - MASS_H2O)
          : (k == 2) ? (m - MASS_NH3)
          : (k == 3) ? (m * 0.5f)
          : m;

        // jnp.round = round-half-to-even = rintf (v_rndne_f32)
        int idx = (int)rintf(m * 10.0f) - (WIN / 2);
        bool valid = (idx >= 0) && (idx <= MAX_MZ - WIN);
        int safe = valid ? idx : 0;               // matches reference jnp.where
        float s = spectrum[safe + w];             // always in-bounds, L1/L2-resident
        vals[j] = s * (valid ? lmask : 0.0f);
    }

    float4 r;
    r.x = vals[0]; r.y = vals[1]; r.z = vals[2]; r.w = vals[3];
    reinterpret_cast<float4*>(out)[tid] = r;
}

extern "C" void kernel_launch(void* const* d_in, const int* in_sizes, int n_in,
                              void* d_out, int out_size, void* d_ws, size_t ws_size,
                              hipStream_t stream) {
    const float* spectrum    = (const float*)d_in[0];
    const float* pepmass     = (const float*)d_in[1];
    const float* prefix_mass = (const float*)d_in[2];
    const float* masses      = (const float*)d_in[3];
    const int*   direction   = (const int*)d_in[4];
    float* out = (float*)d_out;

    int n_vec4 = out_size / 4;   // 17,039,360
    int block = 256;
    int grid = (n_vec4 + block - 1) / block;
    intensity_kernel<<<grid, block, 0, stream>>>(
        spectrum, pepmass, prefix_mass, masses, direction, out, n_vec4);
}

// Round 2
// 308.218 us; speedup vs baseline: 1.0771x; 1.0771x over previous
//
#include <hip/hip_runtime.h>
#include <hip/hip_fp16.h>

// DeepNovo intensity-window gather, round 2.
// Bottleneck analysis R1: 332us @ 0.82 TB/s write BW vs 43us write floor.
// Stores are perfectly coalesced; VALU ~24us machine-wide; the remaining pipe
// is the divergent spectrum gather through L1 (120KB table > 32KB L1, ~26-40
// distinct lines per wave-load, TA serializes divergent addresses).
// Fix: stage spectrum in LDS as fp16 (60KB static __shared__ -> 2 blocks/CU,
// 16 waves/CU). LDS handles divergent gathers at ~32 addr/cycle with only
// ~1.7x expected bank-conflict cost. fp16 abs err <= 4.9e-4 on [0,1) values,
// harness threshold 2e-2 -> safe.

#define MASS_H2O 18.01056f
#define MASS_NH3 17.02655f

constexpr int MAX_MZ = 30000;
constexpr int WIN = 10;
constexpr int VOCAB = 26;
constexpr int BLOCK = 512;
constexpr int GRID = 512;   // 2 blocks/CU (LDS-limited), 262144 threads total

__global__ __launch_bounds__(BLOCK, 4) void intensity_kernel(
    const float* __restrict__ spectrum,
    const float* __restrict__ pepmass,
    const float* __restrict__ prefix_mass,
    const float* __restrict__ masses,
    const int*   __restrict__ dir_p,
    float* __restrict__ out,
    int n_vec4)
{
    __shared__ __half sspec[MAX_MZ];   // 60,000 B static LDS

    // Stage spectrum fp32 -> fp16 into LDS (L2-served after first block).
    {
        const float2* sp2 = reinterpret_cast<const float2*>(spectrum);
        __half2* dst = reinterpret_cast<__half2*>(sspec);
        for (int i = threadIdx.x; i < MAX_MZ / 2; i += BLOCK) {
            float2 v = sp2[i];
            dst[i] = __floats2half2_rn(v.x, v.y);
        }
    }
    __syncthreads();

    const int dir = dir_p[0];
    const int stride = GRID * BLOCK;

    // Grid-stride over output float4s: 17,039,360 / 262,144 = exactly 65 iters.
    for (int tid = blockIdx.x * BLOCK + threadIdx.x; tid < n_vec4; tid += stride) {
        // Each (b,v) group owns 80 contiguous floats = 20 float4s.
        int g = tid / 20;
        int q = tid - g * 20;
        int b = g / VOCAB;
        int v = g - b * VOCAB;

        float pm = pepmass[b];
        float pf = prefix_mass[b];
        float ms = masses[v];

        float t = pf + ms;
        float u = pm - t;
        float cb = (dir == 0) ? t : u;
        float cy = (dir == 0) ? u : t;

        // vocab rows {PAD, GO, EOS} = {0,1,2} zeroed in both directions
        float lmask = (v > 2) ? 1.0f : 0.0f;

        float vals[4];
#pragma unroll
        for (int j = 0; j < 4; ++j) {
            int e   = 4 * q + j;       // element within the 80-float group
            int ion = e / WIN;         // 0..7
            int w   = e - ion * WIN;   // 0..9

            float m = (ion < 4) ? cb : cy;
            int k = ion & 3;
            m = (k == 1) ? (m - MASS_H2O)
              : (k == 2) ? (m - MASS_NH3)
              : (k == 3) ? (m * 0.5f)
              : m;

            // jnp.round = round-half-to-even = rintf (v_rndne_f32)
            int idx = (int)rintf(m * 10.0f) - (WIN / 2);
            bool valid = (idx >= 0) && (idx <= MAX_MZ - WIN);
            int safe = valid ? idx : 0;               // matches jnp.where
            float s = __half2float(sspec[safe + w]);  // LDS gather
            vals[j] = valid ? (s * lmask) : 0.0f;
        }

        float4 r;
        r.x = vals[0]; r.y = vals[1]; r.z = vals[2]; r.w = vals[3];
        reinterpret_cast<float4*>(out)[tid] = r;
    }
}

extern "C" void kernel_launch(void* const* d_in, const int* in_sizes, int n_in,
                              void* d_out, int out_size, void* d_ws, size_t ws_size,
                              hipStream_t stream) {
    const float* spectrum    = (const float*)d_in[0];
    const float* pepmass     = (const float*)d_in[1];
    const float* prefix_mass = (const float*)d_in[2];
    const float* masses      = (const float*)d_in[3];
    const int*   direction   = (const int*)d_in[4];
    float* out = (float*)d_out;

    int n_vec4 = out_size / 4;   // 17,039,360
    intensity_kernel<<<GRID, BLOCK, 0, stream>>>(
        spectrum, pepmass, prefix_mass, masses, direction, out, n_vec4);
}